// Round 2
// baseline (3013.345 us; speedup 1.0000x reference)
//
#include <hip/hip_runtime.h>
#include <cmath>

constexpr int KTOT = 7 * 64;     // 448 = 6 scaled-aggregator slots + linear slot
constexpr int ZSTR = KTOT + 1;   // 449, odd stride -> conflict-free broadcast reads

// Build combined transposed weight Wt[slot][d][o], slot = a*3+s for pre_w, slot 6 = lin_w.
__global__ void k_build_wt(const float* __restrict__ pre_w,
                           const float* __restrict__ lin_w,
                           float* __restrict__ Wt) {
  int idx = blockIdx.x * 256 + threadIdx.x;
  if (idx >= KTOT * 64) return;
  int slot = idx >> 12;        // /4096
  int rem  = idx & 4095;
  int d = rem >> 6;
  int o = rem & 63;
  float v = (slot < 6) ? pre_w[slot * 4096 + o * 64 + d]   // pre_w[a][s][o][d]
                       : lin_w[o * 64 + d];
  Wt[idx] = v;
}

// One thread per (edge, 4-dim chunk): gather x[src] float4, atomic-add into s1/s2[dst].
__global__ void k_scatter(const float4* __restrict__ x4,
                          const int* __restrict__ erow,
                          const int* __restrict__ ecol,
                          float* __restrict__ s1,
                          float* __restrict__ s2,
                          int* __restrict__ deg,
                          int ne) {
  int tid = blockIdx.x * 256 + threadIdx.x;
  int e = tid >> 4;
  if (e >= ne) return;
  int p = tid & 15;
  int dst = erow[e];
  int src = ecol[e];
  float4 v = x4[src * 16 + p];
  float* a1 = s1 + dst * 64 + p * 4;
  float* a2 = s2 + dst * 64 + p * 4;
  unsafeAtomicAdd(a1 + 0, v.x);
  unsafeAtomicAdd(a1 + 1, v.y);
  unsafeAtomicAdd(a1 + 2, v.z);
  unsafeAtomicAdd(a1 + 3, v.w);
  unsafeAtomicAdd(a2 + 0, v.x * v.x);
  unsafeAtomicAdd(a2 + 1, v.y * v.y);
  unsafeAtomicAdd(a2 + 2, v.z * v.z);
  unsafeAtomicAdd(a2 + 3, v.w * v.w);
  if (p == 0) atomicAdd(deg + dst, 1);
}

// Dense phase: per node build z[448] in LDS, out[n] = z @ Wt + bias.
// Block = 4 waves; each wave owns 4 nodes (lane = ns*16+og; thread -> 4 outputs).
// Wt (114.7KB f32) staged once per block in LDS.
// NOTE: s1 aliases the output buffer; each wave reads its nodes' s1 rows
// (into LDS, consumed) strictly before overwriting them with the result.
__global__ void __launch_bounds__(256)
k_dense(const float* __restrict__ x,
        const float* __restrict__ s1,
        const float* __restrict__ s2,
        const int* __restrict__ deg,
        const float* __restrict__ Wt,
        const float* __restrict__ bias,
        const float* __restrict__ avgp,
        float* __restrict__ out,
        int nn) {
  extern __shared__ float lds[];
  float* wlds = lds;                  // [448][64]
  float* zlds = lds + KTOT * 64;      // [4 waves][4 nodes][449]
  const float avg = avgp[0];

  {
    const float4* wg = (const float4*)Wt;
    float4* wl = (float4*)wlds;
    for (int i = threadIdx.x; i < KTOT * 16; i += 256) wl[i] = wg[i];
  }
  __syncthreads();

  const int wave = threadIdx.x >> 6;
  const int lane = threadIdx.x & 63;
  const int ns = lane >> 4;    // node within quad
  const int og = lane & 15;    // output group (4 outputs)
  float* zw = zlds + wave * (4 * ZSTR);
  float4 bv = ((const float4*)bias)[og];

  const int nquads = nn >> 2;
  for (int q = blockIdx.x * 4 + wave; q < nquads; q += gridDim.x * 4) {
    // stage z for the 4 nodes; full wave, lane = d
    for (int j = 0; j < 4; ++j) {
      int n = q * 4 + j;
      int d = lane;
      float m   = s1[n * 64 + d];
      float s2v = s2[n * 64 + d];
      float xv  = x [n * 64 + d];
      float var = fmaxf(s2v - m * m, 0.0f) + 1e-7f;
      float sd  = sqrtf(var);
      float logd = logf((float)deg[n] + 1.0f);
      float f2 = logd / avg;
      float f3 = avg / (logd + 1e-7f);
      float* zr = zw + j * ZSTR;
      zr[d]       = m;
      zr[64 + d]  = m * f2;
      zr[128 + d] = m * f3;
      zr[192 + d] = sd;
      zr[256 + d] = sd * f2;
      zr[320 + d] = sd * f3;
      zr[384 + d] = xv;
    }
    // wave-local LDS producer->consumer (cross-lane): drain lgkm before reads
    asm volatile("s_waitcnt lgkmcnt(0)" ::: "memory");

    const float* zrow = zw + ns * ZSTR;
    const float4* wrow = (const float4*)wlds;
    float a0 = 0.f, a1 = 0.f, a2 = 0.f, a3 = 0.f;
#pragma unroll 8
    for (int k = 0; k < KTOT; ++k) {
      float zv = zrow[k];              // broadcast within 16-lane group
      float4 wv = wrow[k * 16 + og];   // 256B contiguous across og
      a0 = fmaf(zv, wv.x, a0);
      a1 = fmaf(zv, wv.y, a1);
      a2 = fmaf(zv, wv.z, a2);
      a3 = fmaf(zv, wv.w, a3);
    }
    int n = q * 4 + ns;
    ((float4*)out)[n * 16 + og] =
        make_float4(a0 + bv.x, a1 + bv.y, a2 + bv.z, a3 + bv.w);
  }
}

extern "C" void kernel_launch(void* const* d_in, const int* in_sizes, int n_in,
                              void* d_out, int out_size, void* d_ws, size_t ws_size,
                              hipStream_t stream) {
  const float* x     = (const float*)d_in[0];
  const int*   erow  = (const int*)d_in[1];
  const int*   ecol  = (const int*)d_in[2];
  const float* pre_w = (const float*)d_in[3];
  const float* lin_w = (const float*)d_in[4];
  const float* bias  = (const float*)d_in[5];
  const float* avgp  = (const float*)d_in[6];
  float* out = (float*)d_out;

  int nn = in_sizes[0] / 64;
  int ne = in_sizes[1];

  // s1 lives in d_out (exactly nn*64 floats) to keep workspace small (~26 MB).
  float* s1 = out;
  float* s2 = (float*)d_ws;
  int*   deg = (int*)(s2 + (size_t)nn * 64);
  float* Wt  = (float*)(deg + nn);

  // zero s2 + deg (contiguous in ws) and s1 (= d_out)
  hipMemsetAsync(d_ws, 0, ((size_t)nn * 64 + (size_t)nn) * 4, stream);
  hipMemsetAsync((void*)s1, 0, (size_t)nn * 64 * 4, stream);

  k_build_wt<<<(KTOT * 64 + 255) / 256, 256, 0, stream>>>(pre_w, lin_w, Wt);
  k_scatter<<<(ne * 16 + 255) / 256, 256, 0, stream>>>(
      (const float4*)x, erow, ecol, s1, s2, deg, ne);
  k_dense<<<512, 256, (size_t)(KTOT * 64 + 4 * 4 * ZSTR) * 4, stream>>>(
      x, s1, s2, deg, Wt, bias, avgp, out, nn);
}

// Round 3
// 487.469 us; speedup vs baseline: 6.1816x; 6.1816x over previous
//
#include <hip/hip_runtime.h>
#include <cmath>

// ---------------- configuration ----------------
constexpr int D = 64;           // feature dim (in = out)
constexpr int NSLOT = 7;        // 6 scaled aggregator slots + 1 linear slot
constexpr int KTOT = NSLOT * D; // 448
constexpr int KSTEPS = KTOT / 32;  // 14 MFMA K-steps
constexpr int ZROW = KTOT + 8;  // 456 bf16 per z row (pad -> 2-way banks on b128)

typedef __attribute__((ext_vector_type(8))) short bf16x8;
typedef __attribute__((ext_vector_type(4))) float f32x4;

// round-to-nearest-even fp32 -> bf16 (finite inputs only)
static __device__ inline ushort bfq(float f) {
  unsigned u = __builtin_bit_cast(unsigned, f);
  unsigned r = (u + 0x7FFFu + ((u >> 16) & 1u)) >> 16;
  return (ushort)r;
}

// ---------------- weight prep ----------------
// Wt[k][o] fp32, k = slot*64 + d; slot<6 from pre_w[a][s][o][d] (slot=a*3+s), slot 6 = lin_w[o][d]
__global__ void k_build_wt(const float* __restrict__ pre_w,
                           const float* __restrict__ lin_w,
                           float* __restrict__ Wt) {
  int idx = blockIdx.x * 256 + threadIdx.x;
  if (idx >= KTOT * D) return;
  int k = idx >> 6;        // 0..447
  int o = idx & 63;
  int slot = k >> 6;
  int d = k & 63;
  float v = (slot < 6) ? pre_w[slot * 4096 + o * 64 + d] : lin_w[o * 64 + d];
  Wt[idx] = v;
}

// Pack W into MFMA B-fragment order (bf16):
// Bfrag[ks][ot][lane][j] = bf16( W[ks*32 + (lane>>4)*8 + j][ot*16 + (lane&15)] )
__global__ void k_pack_b(const float* __restrict__ Wt, ushort* __restrict__ Bfrag) {
  int idx = blockIdx.x * 256 + threadIdx.x;   // over 14*4*64*8 = 28672
  if (idx >= KSTEPS * 4 * 64 * 8) return;
  int j = idx & 7;
  int lane = (idx >> 3) & 63;
  int ot = (idx >> 9) & 3;
  int ks = idx >> 11;
  int k = ks * 32 + (lane >> 4) * 8 + j;
  int o = ot * 16 + (lane & 15);
  Bfrag[idx] = bfq(Wt[k * 64 + o]);
}

// ---------------- CSR build ----------------
__global__ void k_hist(const int* __restrict__ erow, int* __restrict__ cnt, int ne) {
  int e = blockIdx.x * 256 + threadIdx.x;
  if (e < ne) atomicAdd(&cnt[erow[e]], 1);
}

#define SCAN_B 1024
__global__ void k_scan1(const int* __restrict__ cnt, int* __restrict__ part,
                        int* __restrict__ bsums, int n) {
  __shared__ int t[SCAN_B];
  int i = blockIdx.x * SCAN_B + threadIdx.x;
  int v = (i < n) ? cnt[i] : 0;
  t[threadIdx.x] = v;
  __syncthreads();
  for (int off = 1; off < SCAN_B; off <<= 1) {
    int u = (threadIdx.x >= (unsigned)off) ? t[threadIdx.x - off] : 0;
    __syncthreads();
    t[threadIdx.x] += u;
    __syncthreads();
  }
  if (i < n) part[i] = t[threadIdx.x];
  if (threadIdx.x == SCAN_B - 1) bsums[blockIdx.x] = t[SCAN_B - 1];
}

__global__ void k_scan2(int* __restrict__ bsums, int nb) {  // single block, 128 thr
  __shared__ int t[128];
  int v = (threadIdx.x < (unsigned)nb) ? bsums[threadIdx.x] : 0;
  t[threadIdx.x] = v;
  __syncthreads();
  for (int off = 1; off < 128; off <<= 1) {
    int u = (threadIdx.x >= (unsigned)off) ? t[threadIdx.x - off] : 0;
    __syncthreads();
    t[threadIdx.x] += u;
    __syncthreads();
  }
  if (threadIdx.x < (unsigned)nb) bsums[threadIdx.x] = t[threadIdx.x] - v;  // exclusive
}

// rowptr[i+1] = inclusive; cnt[i] <- exclusive (becomes write cursor "pos")
__global__ void k_scan3(int* __restrict__ cnt, const int* __restrict__ part,
                        const int* __restrict__ bsums, int* __restrict__ rowptr, int n) {
  int i = blockIdx.x * 256 + threadIdx.x;
  if (i >= n) return;
  int incl = part[i] + bsums[i >> 10];
  rowptr[i + 1] = incl;
  if (i == 0) rowptr[0] = 0;
  cnt[i] = incl - cnt[i];
}

__global__ void k_reorder(const int* __restrict__ erow, const int* __restrict__ ecol,
                          int* __restrict__ pos, int* __restrict__ esrc, int ne) {
  int e = blockIdx.x * 256 + threadIdx.x;
  if (e < ne) {
    int p = atomicAdd(&pos[erow[e]], 1);
    esrc[p] = ecol[e];
  }
}

// ---------------- fused aggregate + MFMA dense ----------------
// Block = 4 waves, 64 nodes. Wave w: nodes [blk*64 + w*16, +16).
// Phase 1 (per node, lane=dim): pull-gather sum/sumsq over CSR range, build z (7 slots) bf16 in LDS.
// Phase 2: 16x16x32 bf16 MFMA, A = z tile (LDS), B = pre-packed W frags (global, L2-resident).
__global__ void __launch_bounds__(256)
k_agg_dense(const float* __restrict__ x,
            const int* __restrict__ rowptr,
            const int* __restrict__ esrc,
            const ushort* __restrict__ Bfrag,
            const float* __restrict__ bias,
            const float* __restrict__ avgp,
            float* __restrict__ out,
            int nn) {
  __shared__ ushort zs[4 * 16 * ZROW];   // 58368 B
  const float avg = avgp[0];
  const int wave = threadIdx.x >> 6;
  const int lane = threadIdx.x & 63;
  const int n0 = blockIdx.x * 64 + wave * 16;
  ushort* zw = zs + wave * 16 * ZROW;

  // ---- phase 1: aggregate 16 nodes ----
  for (int j = 0; j < 16; ++j) {
    int n = n0 + j;
    int start = rowptr[n], end = rowptr[n + 1];
    float a1 = 0.f, a2 = 0.f;
    for (int base = start; base < end; base += 64) {
      int nb = end - base;
      if (nb > 64) nb = 64;
      int sv = (base + lane < end) ? esrc[base + lane] : 0;
      int k = 0;
      for (; k + 7 < nb; k += 8) {   // 8 loads in flight
        int t0 = __shfl(sv, k + 0), t1 = __shfl(sv, k + 1);
        int t2 = __shfl(sv, k + 2), t3 = __shfl(sv, k + 3);
        int t4 = __shfl(sv, k + 4), t5 = __shfl(sv, k + 5);
        int t6 = __shfl(sv, k + 6), t7 = __shfl(sv, k + 7);
        float v0 = x[t0 * 64 + lane], v1 = x[t1 * 64 + lane];
        float v2 = x[t2 * 64 + lane], v3 = x[t3 * 64 + lane];
        float v4 = x[t4 * 64 + lane], v5 = x[t5 * 64 + lane];
        float v6 = x[t6 * 64 + lane], v7 = x[t7 * 64 + lane];
        a1 += ((v0 + v1) + (v2 + v3)) + ((v4 + v5) + (v6 + v7));
        a2 = fmaf(v0, v0, a2); a2 = fmaf(v1, v1, a2);
        a2 = fmaf(v2, v2, a2); a2 = fmaf(v3, v3, a2);
        a2 = fmaf(v4, v4, a2); a2 = fmaf(v5, v5, a2);
        a2 = fmaf(v6, v6, a2); a2 = fmaf(v7, v7, a2);
      }
      for (; k < nb; ++k) {
        int t = __shfl(sv, k);
        float v = x[t * 64 + lane];
        a1 += v;
        a2 = fmaf(v, v, a2);
      }
    }
    bool pad = (n >= nn);
    float m = a1;
    float sd = sqrtf(fmaxf(a2 - m * m, 0.f) + 1e-7f);  // relu(s2 - s1^2) + eps
    float degf = (float)(end - start);
    float logd = logf(degf + 1.f);
    float f2 = logd / avg;
    float f3 = avg / (logd + 1e-7f);
    float xv = pad ? 0.f : x[n * 64 + lane];
    if (pad) { m = 0.f; sd = 0.f; f2 = 0.f; f3 = 0.f; }
    ushort* zr = zw + j * ZROW;
    zr[lane]           = bfq(m);
    zr[64 + lane]      = bfq(m * f2);
    zr[128 + lane]     = bfq(m * f3);
    zr[192 + lane]     = bfq(sd);
    zr[256 + lane]     = bfq(sd * f2);
    zr[320 + lane]     = bfq(sd * f3);
    zr[384 + lane]     = bfq(xv);
  }
  // (compiler inserts lgkmcnt waits for same-wave LDS write->read deps; no barrier
  //  needed: each wave reads only its own z slice)

  // ---- phase 2: MFMA ----
  const int col = lane & 15;     // A row (node) / D col provider in frags
  const int kg = lane >> 4;
  const ushort* za = zw + col * ZROW + kg * 8;
  const ushort* bp = Bfrag + lane * 8;
  f32x4 acc0 = {0.f, 0.f, 0.f, 0.f}, acc1 = acc0, acc2 = acc0, acc3 = acc0;
  for (int ks = 0; ks < KSTEPS; ++ks) {
    bf16x8 a = *(const bf16x8*)(za + ks * 32);
    bf16x8 b0 = *(const bf16x8*)(bp + (ks * 4 + 0) * 512);
    bf16x8 b1 = *(const bf16x8*)(bp + (ks * 4 + 1) * 512);
    bf16x8 b2 = *(const bf16x8*)(bp + (ks * 4 + 2) * 512);
    bf16x8 b3 = *(const bf16x8*)(bp + (ks * 4 + 3) * 512);
    acc0 = __builtin_amdgcn_mfma_f32_16x16x32_bf16(a, b0, acc0, 0, 0, 0);
    acc1 = __builtin_amdgcn_mfma_f32_16x16x32_bf16(a, b1, acc1, 0, 0, 0);
    acc2 = __builtin_amdgcn_mfma_f32_16x16x32_bf16(a, b2, acc2, 0, 0, 0);
    acc3 = __builtin_amdgcn_mfma_f32_16x16x32_bf16(a, b3, acc3, 0, 0, 0);
  }
  // C/D: col = lane&15 (output o), row = kg*4 + i (node) [m89-verified]
  {
    float b0 = bias[0 * 16 + col], b1 = bias[1 * 16 + col];
    float b2 = bias[2 * 16 + col], b3 = bias[3 * 16 + col];
#pragma unroll
    for (int i = 0; i < 4; ++i) {
      int n = n0 + kg * 4 + i;
      if (n < nn) {
        float* orow = out + n * 64;
        orow[0 * 16 + col] = acc0[i] + b0;
        orow[1 * 16 + col] = acc1[i] + b1;
        orow[2 * 16 + col] = acc2[i] + b2;
        orow[3 * 16 + col] = acc3[i] + b3;
      }
    }
  }
}

// ---------------- exact fp32 fixup for deg-0 nodes (bf16 would amplify f3=avg/1e-7) ----
__global__ void k_fixup(const int* __restrict__ rowptr, const float* __restrict__ x,
                        const float* __restrict__ Wt, const float* __restrict__ bias,
                        const float* __restrict__ avgp, float* __restrict__ out, int nn) {
  int n = blockIdx.x * 256 + threadIdx.x;
  if (n >= nn) return;
  if (rowptr[n + 1] != rowptr[n]) return;   // only deg == 0 (expected ~0 nodes)
  float avg = avgp[0];
  float sd = sqrtf(1e-7f);
  float f3 = avg / 1e-7f;
  for (int o = 0; o < 64; ++o) {
    float acc = bias[o];
    for (int d = 0; d < 64; ++d) {
      acc += sd * Wt[(192 + d) * 64 + o];            // sd * identity slot
      acc += sd * f3 * Wt[(320 + d) * 64 + o];       // sd * attenuation slot
      acc += x[n * 64 + d] * Wt[(384 + d) * 64 + o]; // linear slot
    }
    out[n * 64 + o] = acc;
  }
}

// ---------------- launch ----------------
extern "C" void kernel_launch(void* const* d_in, const int* in_sizes, int n_in,
                              void* d_out, int out_size, void* d_ws, size_t ws_size,
                              hipStream_t stream) {
  const float* x     = (const float*)d_in[0];
  const int*   erow  = (const int*)d_in[1];
  const int*   ecol  = (const int*)d_in[2];
  const float* pre_w = (const float*)d_in[3];
  const float* lin_w = (const float*)d_in[4];
  const float* bias  = (const float*)d_in[5];
  const float* avgp  = (const float*)d_in[6];
  float* out = (float*)d_out;

  int nn = in_sizes[0] / 64;
  int ne = in_sizes[1];
  int npad = ((nn + 127) / 128) * 128;        // 100096, divisible by 64
  int nsb = (npad + SCAN_B - 1) / SCAN_B;     // scan blocks (98)

  // workspace layout (all offsets 256B-aligned)
  char* w = (char*)d_ws;
  auto align = [](size_t v) { return (v + 255) & ~(size_t)255; };
  size_t off = 0;
  int* esrc   = (int*)(w + off); off = align(off + (size_t)ne * 4);
  int* cnt    = (int*)(w + off); size_t cnt_off = off; off = align(off + (size_t)npad * 4);
  int* part   = (int*)(w + off); off = align(off + (size_t)npad * 4);
  int* rowptr = (int*)(w + off); off = align(off + (size_t)(npad + 1) * 4);
  int* bsums  = (int*)(w + off); off = align(off + 256 * 4);
  float* Wt   = (float*)(w + off); off = align(off + (size_t)KTOT * 64 * 4);
  ushort* Bfr = (ushort*)(w + off); off = align(off + (size_t)KSTEPS * 4 * 64 * 8 * 2);
  (void)ws_size;

  hipMemsetAsync(w + cnt_off, 0, (size_t)npad * 4, stream);

  k_build_wt<<<(KTOT * 64 + 255) / 256, 256, 0, stream>>>(pre_w, lin_w, Wt);
  k_pack_b<<<(KSTEPS * 4 * 64 * 8 + 255) / 256, 256, 0, stream>>>(Wt, Bfr);
  k_hist<<<(ne + 255) / 256, 256, 0, stream>>>(erow, cnt, ne);
  k_scan1<<<nsb, SCAN_B, 0, stream>>>(cnt, part, bsums, npad);
  k_scan2<<<1, 128, 0, stream>>>(bsums, nsb);
  k_scan3<<<(npad + 255) / 256, 256, 0, stream>>>(cnt, part, bsums, rowptr, npad);
  k_reorder<<<(ne + 255) / 256, 256, 0, stream>>>(erow, ecol, cnt, esrc, ne);
  k_agg_dense<<<npad / 64, 256, 0, stream>>>(x, rowptr, esrc, Bfr, bias, avgp, out, nn);
  k_fixup<<<(nn + 255) / 256, 256, 0, stream>>>(rowptr, x, Wt, bias, avgp, out, nn);
}

// Round 4
// 345.073 us; speedup vs baseline: 8.7325x; 1.4127x over previous
//
#include <hip/hip_runtime.h>
#include <cmath>

constexpr int D = 64;
constexpr int KTOT = 448;          // 7 slots * 64
constexpr int KSTEPS = 14;         // 448 / 32
constexpr int ZROW = 456;          // ushort stride per z row (16B aligned, balanced banks)

typedef __attribute__((ext_vector_type(8))) short bf16x8;
typedef __attribute__((ext_vector_type(4))) float f32x4;

static __device__ inline ushort bfq(float f) {   // fp32 -> bf16 RNE
  unsigned u = __builtin_bit_cast(unsigned, f);
  return (ushort)((u + 0x7FFFu + ((u >> 16) & 1u)) >> 16);
}
static __device__ inline float b2f(ushort h) {
  return __builtin_bit_cast(float, (unsigned)h << 16);
}

// ---------------- fused prep: x->bf16, degree histogram, Wt + Bfrag ----------------
__global__ void k_hist_prep(const float* __restrict__ x,
                            const int* __restrict__ erow,
                            int* __restrict__ cnt,
                            ushort* __restrict__ xh,
                            const float* __restrict__ pre_w,
                            const float* __restrict__ lin_w,
                            float* __restrict__ Wt,
                            ushort* __restrict__ Bfrag,
                            int ne, int total) {
  int i = blockIdx.x * 256 + threadIdx.x;
  if (i < total) xh[i] = bfq(x[i]);
  if (i < ne) atomicAdd(&cnt[erow[i]], 1);
  if (i < KTOT * 64) {
    // Wt[k][o] fp32 (for exact deg-0 fixup)
    int k = i >> 6, o = i & 63;
    int slot = k >> 6, d = k & 63;
    Wt[i] = (slot < 6) ? pre_w[slot * 4096 + o * 64 + d] : lin_w[o * 64 + d];
    // Bfrag[((ks*4+ot)*64+lane)*8+j] = bf16(W[ks*32+(lane>>4)*8+j][ot*16+(lane&15)])
    int j = i & 7, lane = (i >> 3) & 63, ot = (i >> 9) & 3, ks = i >> 11;
    int kk = ks * 32 + (lane >> 4) * 8 + j;
    int oo = ot * 16 + (lane & 15);
    int s2 = kk >> 6, d2 = kk & 63;
    float v = (s2 < 6) ? pre_w[s2 * 4096 + oo * 64 + d2] : lin_w[oo * 64 + d2];
    Bfrag[i] = bfq(v);
  }
}

// ---------------- CSR build (hist above, then scan + reorder) ----------------
#define SCAN_B 1024
__global__ void k_scan1(const int* __restrict__ cnt, int* __restrict__ part,
                        int* __restrict__ bsums, int n) {
  __shared__ int t[SCAN_B];
  int i = blockIdx.x * SCAN_B + threadIdx.x;
  int v = (i < n) ? cnt[i] : 0;
  t[threadIdx.x] = v;
  __syncthreads();
  for (int off = 1; off < SCAN_B; off <<= 1) {
    int u = (threadIdx.x >= (unsigned)off) ? t[threadIdx.x - off] : 0;
    __syncthreads();
    t[threadIdx.x] += u;
    __syncthreads();
  }
  if (i < n) part[i] = t[threadIdx.x];
  if (threadIdx.x == SCAN_B - 1) bsums[blockIdx.x] = t[SCAN_B - 1];
}

__global__ void k_scan2(int* __restrict__ bsums, int nb) {  // 1 block, 128 thr
  __shared__ int t[128];
  int v = (threadIdx.x < (unsigned)nb) ? bsums[threadIdx.x] : 0;
  t[threadIdx.x] = v;
  __syncthreads();
  for (int off = 1; off < 128; off <<= 1) {
    int u = (threadIdx.x >= (unsigned)off) ? t[threadIdx.x - off] : 0;
    __syncthreads();
    t[threadIdx.x] += u;
    __syncthreads();
  }
  if (threadIdx.x < (unsigned)nb) bsums[threadIdx.x] = t[threadIdx.x] - v;  // exclusive
}

__global__ void k_scan3(int* __restrict__ cnt, const int* __restrict__ part,
                        const int* __restrict__ bsums, int* __restrict__ rowptr, int n) {
  int i = blockIdx.x * 256 + threadIdx.x;
  if (i >= n) return;
  int incl = part[i] + bsums[i >> 10];
  rowptr[i + 1] = incl;
  if (i == 0) rowptr[0] = 0;
  cnt[i] = incl - cnt[i];   // exclusive -> write cursor
}

__global__ void k_reorder(const int* __restrict__ erow, const int* __restrict__ ecol,
                          int* __restrict__ pos, int* __restrict__ esrc, int ne) {
  int e = blockIdx.x * 256 + threadIdx.x;
  if (e < ne) {
    int p = atomicAdd(&pos[erow[e]], 1);
    esrc[p] = ecol[e];
  }
}

// ---------------- gather helper: accumulate sum / sumsq over one <=64-edge chunk ----
static __device__ inline void chunk_acc(const ushort* __restrict__ xh, int sv,
                                        int cnt, int lane, float& a1, float& a2) {
  int k = 0;
  for (; k + 15 < cnt; k += 16) {
    float v[16];
#pragma unroll
    for (int u = 0; u < 16; ++u)
      v[u] = b2f(xh[__shfl(sv, k + u) * 64 + lane]);
#pragma unroll
    for (int u = 0; u < 16; ++u) { a1 += v[u]; a2 = fmaf(v[u], v[u], a2); }
  }
  for (; k + 3 < cnt; k += 4) {
    float v[4];
#pragma unroll
    for (int u = 0; u < 4; ++u)
      v[u] = b2f(xh[__shfl(sv, k + u) * 64 + lane]);
#pragma unroll
    for (int u = 0; u < 4; ++u) { a1 += v[u]; a2 = fmaf(v[u], v[u], a2); }
  }
  for (; k < cnt; ++k) {
    float v = b2f(xh[__shfl(sv, k) * 64 + lane]);
    a1 += v; a2 = fmaf(v, v, a2);
  }
}

// ---------------- fused aggregate + MFMA dense ----------------
// Block = 4 waves = 16 nodes. Wave w aggregates nodes [n0+4w, +4) (lane = dim),
// writes bf16 z rows to LDS; barrier; wave w then computes o-tile w (16 cols)
// of the 16x64 output via 14x mfma_16x16x32_bf16 with pre-packed B from L2.
__global__ void __launch_bounds__(256, 6)
k_agg_dense(const ushort* __restrict__ xh,
            const float* __restrict__ x,
            const int* __restrict__ rowptr,
            const int* __restrict__ esrc,
            const ushort* __restrict__ Bfrag,
            const float* __restrict__ bias,
            const float* __restrict__ avgp,
            float* __restrict__ out, int nn) {
  __shared__ __align__(16) ushort zs[16 * ZROW];   // 14592 B
  const float avg = avgp[0];
  const int wave = threadIdx.x >> 6, lane = threadIdx.x & 63;
  const int n0 = blockIdx.x * 16;
  const int nw = n0 + wave * 4;

  // prefetch rowptr[nw..nw+4] and first edge-chunk of each node (loads overlap)
  int rpv = (lane < 5) ? rowptr[nw + lane] : 0;
  int e0 = __shfl(rpv, 0), e1 = __shfl(rpv, 1), e2 = __shfl(rpv, 2),
      e3 = __shfl(rpv, 3), e4 = __shfl(rpv, 4);
  int sv0 = (e0 + lane < e1) ? esrc[e0 + lane] : 0;
  int sv1 = (e1 + lane < e2) ? esrc[e1 + lane] : 0;
  int sv2 = (e2 + lane < e3) ? esrc[e2 + lane] : 0;
  int sv3 = (e3 + lane < e4) ? esrc[e3 + lane] : 0;

#define DO_NODE(J, SJ, EJ, SVJ)                                           \
  {                                                                       \
    int n = nw + J;                                                       \
    float a1 = 0.f, a2 = 0.f;                                             \
    int nb = EJ - SJ; if (nb > 64) nb = 64;                               \
    chunk_acc(xh, SVJ, nb, lane, a1, a2);                                 \
    for (int base = SJ + 64; base < EJ; base += 64) {                     \
      int c = EJ - base; if (c > 64) c = 64;                              \
      int sv = (base + lane < EJ) ? esrc[base + lane] : 0;                \
      chunk_acc(xh, sv, c, lane, a1, a2);                                 \
    }                                                                     \
    float m = a1;                                                         \
    float sd = sqrtf(fmaxf(a2 - m * m, 0.f) + 1e-7f);                     \
    float degf = (float)(EJ - SJ);                                        \
    float logd = logf(degf + 1.f);                                        \
    float f2 = logd / avg;                                                \
    float f3 = avg / (logd + 1e-7f);                                      \
    float xv = (n < nn) ? x[n * 64 + lane] : 0.f;                         \
    if (n >= nn) { m = 0.f; sd = 0.f; f2 = 0.f; f3 = 0.f; }               \
    ushort* zr = zs + (wave * 4 + J) * ZROW;                              \
    zr[lane]       = bfq(m);                                              \
    zr[64 + lane]  = bfq(m * f2);                                         \
    zr[128 + lane] = bfq(m * f3);                                         \
    zr[192 + lane] = bfq(sd);                                             \
    zr[256 + lane] = bfq(sd * f2);                                        \
    zr[320 + lane] = bfq(sd * f3);                                        \
    zr[384 + lane] = bfq(xv);                                             \
  }
  DO_NODE(0, e0, e1, sv0)
  DO_NODE(1, e1, e2, sv1)
  DO_NODE(2, e2, e3, sv2)
  DO_NODE(3, e3, e4, sv3)
#undef DO_NODE

  __syncthreads();   // all 16 z rows visible to all waves

  // ---- MFMA: A = z tile (16 nodes x 448), B = wave's 16-col tile ----
  const int r = lane & 15, kg = lane >> 4;
  const ushort* za = zs + r * ZROW + kg * 8;
  const ushort* bp = Bfrag + (wave * 64 + lane) * 8;
  f32x4 acc = {0.f, 0.f, 0.f, 0.f};
#pragma unroll
  for (int ks = 0; ks < KSTEPS; ++ks) {
    bf16x8 a = *(const bf16x8*)(za + ks * 32);
    bf16x8 b = *(const bf16x8*)(bp + ks * 2048);
    acc = __builtin_amdgcn_mfma_f32_16x16x32_bf16(a, b, acc, 0, 0, 0);
  }
  float bc = bias[wave * 16 + r];
#pragma unroll
  for (int i = 0; i < 4; ++i) {
    int n = n0 + kg * 4 + i;          // C/D: col = lane&15, row = kg*4+i
    if (n < nn) out[n * 64 + wave * 16 + r] = acc[i] + bc;
  }
}

// ---------------- exact fp32 fixup for deg-0 nodes ----------------
__global__ void k_fixup(const int* __restrict__ rowptr, const float* __restrict__ x,
                        const float* __restrict__ Wt, const float* __restrict__ bias,
                        const float* __restrict__ avgp, float* __restrict__ out, int nn) {
  int n = blockIdx.x * 256 + threadIdx.x;
  if (n >= nn) return;
  if (rowptr[n + 1] != rowptr[n]) return;
  float avg = avgp[0];
  float sd = sqrtf(1e-7f);
  float f3 = avg / 1e-7f;
  for (int o = 0; o < 64; ++o) {
    float acc = bias[o];
    for (int d = 0; d < 64; ++d) {
      acc += sd * Wt[(192 + d) * 64 + o];
      acc += sd * f3 * Wt[(320 + d) * 64 + o];
      acc += x[n * 64 + d] * Wt[(384 + d) * 64 + o];
    }
    out[n * 64 + o] = acc;
  }
}

// ---------------- launch ----------------
extern "C" void kernel_launch(void* const* d_in, const int* in_sizes, int n_in,
                              void* d_out, int out_size, void* d_ws, size_t ws_size,
                              hipStream_t stream) {
  const float* x     = (const float*)d_in[0];
  const int*   erow  = (const int*)d_in[1];
  const int*   ecol  = (const int*)d_in[2];
  const float* pre_w = (const float*)d_in[3];
  const float* lin_w = (const float*)d_in[4];
  const float* bias  = (const float*)d_in[5];
  const float* avgp  = (const float*)d_in[6];
  float* out = (float*)d_out;

  int nn = in_sizes[0] / 64;
  int ne = in_sizes[1];
  int total = nn * 64;
  int npad = ((nn + 15) / 16) * 16;
  int nsb = (npad + SCAN_B - 1) / SCAN_B;

  char* w = (char*)d_ws;
  auto align = [](size_t v) { return (v + 255) & ~(size_t)255; };
  size_t off = 0;
  ushort* xh   = (ushort*)(w + off); off = align(off + (size_t)total * 2);
  int* esrc    = (int*)(w + off); off = align(off + (size_t)ne * 4);
  int* cnt     = (int*)(w + off); size_t cnt_off = off; off = align(off + (size_t)npad * 4);
  int* part    = (int*)(w + off); off = align(off + (size_t)npad * 4);
  int* rowptr  = (int*)(w + off); off = align(off + (size_t)(npad + 1) * 4);
  int* bsums   = (int*)(w + off); off = align(off + 256 * 4);
  float* Wt    = (float*)(w + off); off = align(off + (size_t)KTOT * 64 * 4);
  ushort* Bfr  = (ushort*)(w + off); off = align(off + (size_t)KSTEPS * 4 * 64 * 8 * 2);
  (void)ws_size;

  hipMemsetAsync(w + cnt_off, 0, (size_t)npad * 4, stream);

  int gprep = (total + 255) / 256;   // total (6.4M) >= ne and >= 28672
  k_hist_prep<<<gprep, 256, 0, stream>>>(x, erow, cnt, xh, pre_w, lin_w, Wt, Bfr,
                                         ne, total);
  k_scan1<<<nsb, SCAN_B, 0, stream>>>(cnt, part, bsums, npad);
  k_scan2<<<1, 128, 0, stream>>>(bsums, nsb);
  k_scan3<<<(npad + 255) / 256, 256, 0, stream>>>(cnt, part, bsums, rowptr, npad);
  k_reorder<<<(ne + 255) / 256, 256, 0, stream>>>(erow, ecol, cnt, esrc, ne);
  k_agg_dense<<<npad / 16, 256, 0, stream>>>(xh, x, rowptr, esrc, Bfr, bias, avgp,
                                             out, nn);
  k_fixup<<<(nn + 255) / 256, 256, 0, stream>>>(rowptr, x, Wt, bias, avgp, out, nn);
}

// Round 5
// 292.941 us; speedup vs baseline: 10.2865x; 1.1780x over previous
//
#include <hip/hip_runtime.h>
#include <cmath>

constexpr int D = 64;
constexpr int KTOT = 448;          // 7 slots * 64
constexpr int KSTEPS = 14;         // 448 / 32
constexpr int ZROW = 456;          // ushort stride per z row

typedef __attribute__((ext_vector_type(8))) short bf16x8;
typedef __attribute__((ext_vector_type(4))) float f32x4;

static __device__ inline ushort bfq(float f) {   // fp32 -> bf16 RNE
  unsigned u = __builtin_bit_cast(unsigned, f);
  return (ushort)((u + 0x7FFFu + ((u >> 16) & 1u)) >> 16);
}
static __device__ inline float b2f(ushort h) {
  return __builtin_bit_cast(float, (unsigned)h << 16);
}

// ---------------- fused prep: x->bf16, degree histogram, Wt + Bfrag ----------------
__global__ void k_hist_prep(const float* __restrict__ x,
                            const int* __restrict__ erow,
                            int* __restrict__ cnt,
                            ushort* __restrict__ xh,
                            const float* __restrict__ pre_w,
                            const float* __restrict__ lin_w,
                            float* __restrict__ Wt,
                            ushort* __restrict__ Bfrag,
                            int ne, int total) {
  int i = blockIdx.x * 256 + threadIdx.x;
  if (i < total) xh[i] = bfq(x[i]);
  if (i < ne) atomicAdd(&cnt[erow[i]], 1);
  if (i < KTOT * 64) {
    int k = i >> 6, o = i & 63;
    int slot = k >> 6, d = k & 63;
    Wt[i] = (slot < 6) ? pre_w[slot * 4096 + o * 64 + d] : lin_w[o * 64 + d];
    // Bfrag[((ks*4+ot)*64+lane)*8+j] = bf16(W[ks*32+(lane>>4)*8+j][ot*16+(lane&15)])
    int j = i & 7, lane = (i >> 3) & 63, ot = (i >> 9) & 3, ks = i >> 11;
    int kk = ks * 32 + (lane >> 4) * 8 + j;
    int oo = ot * 16 + (lane & 15);
    int s2 = kk >> 6, d2 = kk & 63;
    float v = (s2 < 6) ? pre_w[s2 * 4096 + oo * 64 + d2] : lin_w[oo * 64 + d2];
    Bfrag[i] = bfq(v);
  }
}

// ---------------- scans ----------------
#define SCAN_B 1024
__global__ void k_scan1(const int* __restrict__ cnt, int* __restrict__ part,
                        int* __restrict__ bsums, int n) {
  __shared__ int t[SCAN_B];
  int i = blockIdx.x * SCAN_B + threadIdx.x;
  int v = (i < n) ? cnt[i] : 0;
  t[threadIdx.x] = v;
  __syncthreads();
  for (int off = 1; off < SCAN_B; off <<= 1) {
    int u = (threadIdx.x >= (unsigned)off) ? t[threadIdx.x - off] : 0;
    __syncthreads();
    t[threadIdx.x] += u;
    __syncthreads();
  }
  if (i < n) part[i] = t[threadIdx.x];
  if (threadIdx.x == SCAN_B - 1) bsums[blockIdx.x] = t[SCAN_B - 1];
}

__global__ void k_scan2(int* __restrict__ bsums, int nb) {  // 1 block, 128 thr
  __shared__ int t[128];
  int v = (threadIdx.x < (unsigned)nb) ? bsums[threadIdx.x] : 0;
  t[threadIdx.x] = v;
  __syncthreads();
  for (int off = 1; off < 128; off <<= 1) {
    int u = (threadIdx.x >= (unsigned)off) ? t[threadIdx.x - off] : 0;
    __syncthreads();
    t[threadIdx.x] += u;
    __syncthreads();
  }
  if (threadIdx.x < (unsigned)nb) bsums[threadIdx.x] = t[threadIdx.x] - v;  // exclusive
}

// rowptr, write-cursor (cnt <- exclusive), bucket cursors (bcur[b] = excl at node b*512)
__global__ void k_scan3(int* __restrict__ cnt, const int* __restrict__ part,
                        const int* __restrict__ bsums, int* __restrict__ rowptr,
                        int* __restrict__ bcur, int n) {
  int i = blockIdx.x * 256 + threadIdx.x;
  if (i >= n) return;
  int orig = cnt[i];
  int incl = part[i] + bsums[i >> 10];
  rowptr[i + 1] = incl;
  if (i == 0) rowptr[0] = 0;
  int excl = incl - orig;
  cnt[i] = excl;
  if ((i & 511) == 0) bcur[i >> 9] = excl;
}

// ---------------- phase 1: coarse bucket scatter (packed words, coalesced segments) --
#define BTILE 8192
__global__ void __launch_bounds__(256)
k_binpass(const int* __restrict__ erow, const int* __restrict__ ecol,
          int* __restrict__ bcur, unsigned* __restrict__ pairs, int ne) {
  __shared__ int h[256], gb[256], h2[256];
  int t = threadIdx.x;
  h[t] = 0; h2[t] = 0;
  __syncthreads();
  int base = blockIdx.x * BTILE;
  int lim = ne - base; if (lim > BTILE) lim = BTILE;
  for (int k = t; k < lim; k += 256)
    atomicAdd(&h[erow[base + k] >> 9], 1);
  __syncthreads();
  if (h[t] > 0) gb[t] = atomicAdd(&bcur[t], h[t]);
  __syncthreads();
  for (int k = t; k < lim; k += 256) {
    int dst = erow[base + k];
    int src = ecol[base + k];
    int b = dst >> 9;
    int r = atomicAdd(&h2[b], 1);
    pairs[gb[b] + r] = ((unsigned)(dst & 511) << 17) | (unsigned)src;
  }
}

// ---------------- phase 2: within-bucket exact placement (L2-local) ----------------
__global__ void __launch_bounds__(256)
k_within(const unsigned* __restrict__ pairs, const int* __restrict__ rowptr,
         int* __restrict__ cnt, int* __restrict__ esrc, int nn) {
  int b = blockIdx.x >> 2;
  int q = blockIdx.x & 3;
  int nstart = b << 9;
  int nend = nstart + 512; if (nend > nn) nend = nn;
  int s = rowptr[nstart], e = rowptr[nend];
  int per = (e - s + 3) >> 2;
  int lo = s + q * per;
  int hi = lo + per; if (hi > e) hi = e;
  for (int i = lo + threadIdx.x; i < hi; i += 256) {
    unsigned w = pairs[i];
    int src = (int)(w & 0x1FFFFu);
    int dst = nstart + (int)(w >> 17);
    int p = atomicAdd(&cnt[dst], 1);
    esrc[p] = src;
  }
}

// ---------------- gather helper ----------------
static __device__ inline void chunk_acc(const ushort* __restrict__ xh, int sv,
                                        int cnt, int lane, float& a1, float& a2) {
  int k = 0;
  for (; k + 15 < cnt; k += 16) {
    float v[16];
#pragma unroll
    for (int u = 0; u < 16; ++u)
      v[u] = b2f(xh[__shfl(sv, k + u) * 64 + lane]);
#pragma unroll
    for (int u = 0; u < 16; ++u) { a1 += v[u]; a2 = fmaf(v[u], v[u], a2); }
  }
  for (; k + 3 < cnt; k += 4) {
    float v[4];
#pragma unroll
    for (int u = 0; u < 4; ++u)
      v[u] = b2f(xh[__shfl(sv, k + u) * 64 + lane]);
#pragma unroll
    for (int u = 0; u < 4; ++u) { a1 += v[u]; a2 = fmaf(v[u], v[u], a2); }
  }
  for (; k < cnt; ++k) {
    float v = b2f(xh[__shfl(sv, k) * 64 + lane]);
    a1 += v; a2 = fmaf(v, v, a2);
  }
}

// ---------------- fused aggregate + MFMA dense ----------------
__global__ void __launch_bounds__(256, 6)
k_agg_dense(const ushort* __restrict__ xh,
            const float* __restrict__ x,
            const int* __restrict__ rowptr,
            const int* __restrict__ esrc,
            const ushort* __restrict__ Bfrag,
            const float* __restrict__ bias,
            const float* __restrict__ avgp,
            float* __restrict__ out, int nn) {
  __shared__ __align__(16) ushort zs[16 * ZROW];
  const float avg = avgp[0];
  const int wave = threadIdx.x >> 6, lane = threadIdx.x & 63;
  const int n0 = blockIdx.x * 16;
  const int nw = n0 + wave * 4;

  int rpv = (lane < 5) ? rowptr[nw + lane] : 0;
  int e0 = __shfl(rpv, 0), e1 = __shfl(rpv, 1), e2 = __shfl(rpv, 2),
      e3 = __shfl(rpv, 3), e4 = __shfl(rpv, 4);
  int sv0 = (e0 + lane < e1) ? esrc[e0 + lane] : 0;
  int sv1 = (e1 + lane < e2) ? esrc[e1 + lane] : 0;
  int sv2 = (e2 + lane < e3) ? esrc[e2 + lane] : 0;
  int sv3 = (e3 + lane < e4) ? esrc[e3 + lane] : 0;

#define DO_NODE(J, SJ, EJ, SVJ)                                           \
  {                                                                       \
    int n = nw + J;                                                       \
    float a1 = 0.f, a2 = 0.f;                                             \
    int nb = EJ - SJ; if (nb > 64) nb = 64;                               \
    chunk_acc(xh, SVJ, nb, lane, a1, a2);                                 \
    for (int base = SJ + 64; base < EJ; base += 64) {                     \
      int c = EJ - base; if (c > 64) c = 64;                              \
      int sv = (base + lane < EJ) ? esrc[base + lane] : 0;                \
      chunk_acc(xh, sv, c, lane, a1, a2);                                 \
    }                                                                     \
    float m = a1;                                                         \
    float sd = sqrtf(fmaxf(a2 - m * m, 0.f) + 1e-7f);                     \
    float degf = (float)(EJ - SJ);                                        \
    float logd = logf(degf + 1.f);                                        \
    float f2 = logd / avg;                                                \
    float f3 = avg / (logd + 1e-7f);                                      \
    float xv = (n < nn) ? x[n * 64 + lane] : 0.f;                         \
    if (n >= nn) { m = 0.f; sd = 0.f; f2 = 0.f; f3 = 0.f; }               \
    ushort* zr = zs + (wave * 4 + J) * ZROW;                              \
    zr[lane]       = bfq(m);                                              \
    zr[64 + lane]  = bfq(m * f2);                                         \
    zr[128 + lane] = bfq(m * f3);                                         \
    zr[192 + lane] = bfq(sd);                                             \
    zr[256 + lane] = bfq(sd * f2);                                        \
    zr[320 + lane] = bfq(sd * f3);                                        \
    zr[384 + lane] = bfq(xv);                                             \
  }
  DO_NODE(0, e0, e1, sv0)
  DO_NODE(1, e1, e2, sv1)
  DO_NODE(2, e2, e3, sv2)
  DO_NODE(3, e3, e4, sv3)
#undef DO_NODE

  __syncthreads();

  const int r = lane & 15, kg = lane >> 4;
  const ushort* za = zs + r * ZROW + kg * 8;
  const ushort* bp = Bfrag + (wave * 64 + lane) * 8;
  f32x4 acc = {0.f, 0.f, 0.f, 0.f};
#pragma unroll
  for (int ks = 0; ks < KSTEPS; ++ks) {
    bf16x8 a = *(const bf16x8*)(za + ks * 32);
    bf16x8 b = *(const bf16x8*)(bp + ks * 2048);
    acc = __builtin_amdgcn_mfma_f32_16x16x32_bf16(a, b, acc, 0, 0, 0);
  }
  float bc = bias[wave * 16 + r];
#pragma unroll
  for (int i = 0; i < 4; ++i) {
    int n = n0 + kg * 4 + i;
    if (n < nn) out[n * 64 + wave * 16 + r] = acc[i] + bc;
  }
}

// ---------------- exact fp32 fixup for deg-0 nodes ----------------
__global__ void k_fixup(const int* __restrict__ rowptr, const float* __restrict__ x,
                        const float* __restrict__ Wt, const float* __restrict__ bias,
                        const float* __restrict__ avgp, float* __restrict__ out, int nn) {
  int n = blockIdx.x * 256 + threadIdx.x;
  if (n >= nn) return;
  if (rowptr[n + 1] != rowptr[n]) return;
  float avg = avgp[0];
  float sd = sqrtf(1e-7f);
  float f3 = avg / 1e-7f;
  for (int o = 0; o < 64; ++o) {
    float acc = bias[o];
    for (int d = 0; d < 64; ++d) {
      acc += sd * Wt[(192 + d) * 64 + o];
      acc += sd * f3 * Wt[(320 + d) * 64 + o];
      acc += x[n * 64 + d] * Wt[(384 + d) * 64 + o];
    }
    out[n * 64 + o] = acc;
  }
}

// ---------------- launch ----------------
extern "C" void kernel_launch(void* const* d_in, const int* in_sizes, int n_in,
                              void* d_out, int out_size, void* d_ws, size_t ws_size,
                              hipStream_t stream) {
  const float* x     = (const float*)d_in[0];
  const int*   erow  = (const int*)d_in[1];
  const int*   ecol  = (const int*)d_in[2];
  const float* pre_w = (const float*)d_in[3];
  const float* lin_w = (const float*)d_in[4];
  const float* bias  = (const float*)d_in[5];
  const float* avgp  = (const float*)d_in[6];
  float* out = (float*)d_out;

  int nn = in_sizes[0] / 64;
  int ne = in_sizes[1];
  int total = nn * 64;
  int npad = ((nn + 15) / 16) * 16;
  int nsb = (npad + SCAN_B - 1) / SCAN_B;
  int nbk = (nn + 511) / 512;             // buckets (<=256)

  char* w = (char*)d_ws;
  auto align = [](size_t v) { return (v + 255) & ~(size_t)255; };
  size_t off = 0;
  ushort* xh     = (ushort*)(w + off); off = align(off + (size_t)total * 2);
  int* esrc      = (int*)(w + off); off = align(off + (size_t)ne * 4);
  unsigned* prs  = (unsigned*)(w + off); off = align(off + (size_t)ne * 4);
  int* cnt       = (int*)(w + off); size_t cnt_off = off; off = align(off + (size_t)npad * 4);
  int* part      = (int*)(w + off); off = align(off + (size_t)npad * 4);
  int* rowptr    = (int*)(w + off); off = align(off + (size_t)(npad + 1) * 4);
  int* bsums     = (int*)(w + off); off = align(off + 256 * 4);
  int* bcur      = (int*)(w + off); off = align(off + 256 * 4);
  float* Wt      = (float*)(w + off); off = align(off + (size_t)KTOT * 64 * 4);
  ushort* Bfr    = (ushort*)(w + off); off = align(off + (size_t)KSTEPS * 4 * 64 * 8 * 2);
  (void)ws_size;

  hipMemsetAsync(w + cnt_off, 0, (size_t)npad * 4, stream);

  int gprep = (total + 255) / 256;
  k_hist_prep<<<gprep, 256, 0, stream>>>(x, erow, cnt, xh, pre_w, lin_w, Wt, Bfr,
                                         ne, total);
  k_scan1<<<nsb, SCAN_B, 0, stream>>>(cnt, part, bsums, npad);
  k_scan2<<<1, 128, 0, stream>>>(bsums, nsb);
  k_scan3<<<(npad + 255) / 256, 256, 0, stream>>>(cnt, part, bsums, rowptr, bcur, npad);
  k_binpass<<<(ne + BTILE - 1) / BTILE, 256, 0, stream>>>(erow, ecol, bcur, prs, ne);
  k_within<<<nbk * 4, 256, 0, stream>>>(prs, rowptr, cnt, esrc, nn);
  k_agg_dense<<<npad / 16, 256, 0, stream>>>(xh, x, rowptr, esrc, Bfr, bias, avgp,
                                             out, nn);
  k_fixup<<<(nn + 255) / 256, 256, 0, stream>>>(rowptr, x, Wt, bias, avgp, out, nn);
}

// Round 6
// 204.932 us; speedup vs baseline: 14.7041x; 1.4295x over previous
//
#include <hip/hip_runtime.h>
#include <cmath>

constexpr int D = 64;
constexpr int KTOT = 448;          // 7 slots * 64
constexpr int KSTEPS = 14;         // 448 / 32
constexpr int ZROW = 456;          // ushort stride per z row
constexpr int NBMAX = 256;         // max buckets (512 nodes each)

typedef __attribute__((ext_vector_type(8))) short bf16x8;
typedef __attribute__((ext_vector_type(4))) float f32x4;

static __device__ inline ushort bfq(float f) {   // fp32 -> bf16 RNE
  unsigned u = __builtin_bit_cast(unsigned, f);
  return (ushort)((u + 0x7FFFu + ((u >> 16) & 1u)) >> 16);
}
static __device__ inline float b2f(ushort h) {
  return __builtin_bit_cast(float, (unsigned)h << 16);
}

// ---------------- kA: x->bf16 + Wt/Bfrag + bucket histogram ----------------
// grid covers total/2048 blocks; each block also handles a 2048-edge tile (if any)
__global__ void __launch_bounds__(256)
kA_prep(const float* __restrict__ x, const int* __restrict__ erow,
        int* __restrict__ bucket_cnt, ushort* __restrict__ xh,
        const float* __restrict__ pre_w, const float* __restrict__ lin_w,
        float* __restrict__ Wt, ushort* __restrict__ Bfrag,
        int ne, int total) {
  __shared__ int h[NBMAX];
  int t = threadIdx.x;
  h[t] = 0;
  __syncthreads();

  // x -> bf16, 8 contiguous elements per thread
  int base = blockIdx.x * 2048 + t * 8;
  if (base + 7 < total) {
    const float4* xp = (const float4*)(x + base);
    float4 v0 = xp[0], v1 = xp[1];
    uint4 o;
    o.x = (unsigned)bfq(v0.x) | ((unsigned)bfq(v0.y) << 16);
    o.y = (unsigned)bfq(v0.z) | ((unsigned)bfq(v0.w) << 16);
    o.z = (unsigned)bfq(v1.x) | ((unsigned)bfq(v1.y) << 16);
    o.w = (unsigned)bfq(v1.z) | ((unsigned)bfq(v1.w) << 16);
    *(uint4*)(xh + base) = o;
  } else {
    for (int u = 0; u < 8 && base + u < total; ++u) xh[base + u] = bfq(x[base + u]);
  }

  // Wt (fp32 for fixup) + Bfrag (MFMA B-fragment order)
  int idx = blockIdx.x * 256 + t;
  if (idx < KTOT * 64) {
    int k = idx >> 6, o = idx & 63;
    int slot = k >> 6, d = k & 63;
    Wt[idx] = (slot < 6) ? pre_w[slot * 4096 + o * 64 + d] : lin_w[o * 64 + d];
    int j = idx & 7, lane = (idx >> 3) & 63, ot = (idx >> 9) & 3, ks = idx >> 11;
    int kk = ks * 32 + (lane >> 4) * 8 + j;
    int oo = ot * 16 + (lane & 15);
    int s2 = kk >> 6, d2 = kk & 63;
    float v = (s2 < 6) ? pre_w[s2 * 4096 + oo * 64 + d2] : lin_w[oo * 64 + d2];
    Bfrag[idx] = bfq(v);
  }

  // bucket histogram over this block's 2048-edge tile
  int ebase = blockIdx.x * 2048;
  if (ebase < ne) {
    int elim = ne - ebase; if (elim > 2048) elim = 2048;
    for (int u = t * 8; u < t * 8 + 8; ++u)
      if (u < elim) atomicAdd(&h[erow[ebase + u] >> 9], 1);
    __syncthreads();
    if (h[t] > 0) atomicAdd(&bucket_cnt[t], h[t]);
  }
}

// ---------------- kC: 1-block scan of bucket counts -> bbase, bcur ----------------
__global__ void kC_scan(const int* __restrict__ bucket_cnt, int* __restrict__ bbase,
                        int* __restrict__ bcur, int nbk) {
  __shared__ int ts[NBMAX];
  int t = threadIdx.x;
  int v = (t < nbk) ? bucket_cnt[t] : 0;
  ts[t] = v;
  __syncthreads();
  for (int off = 1; off < NBMAX; off <<= 1) {
    int u = (t >= off) ? ts[t - off] : 0;
    __syncthreads();
    ts[t] += u;
    __syncthreads();
  }
  if (t < nbk) {
    bbase[t + 1] = ts[t];
    bcur[t] = ts[t] - v;   // exclusive
    if (t == 0) bbase[0] = 0;
  }
}

// ---------------- kD: coarse bucket scatter (packed words) ----------------
#define BTILE 8192
__global__ void __launch_bounds__(256)
kD_binpass(const int* __restrict__ erow, const int* __restrict__ ecol,
           int* __restrict__ bcur, unsigned* __restrict__ pairs, int ne) {
  __shared__ int h[NBMAX], gb[NBMAX], h2[NBMAX];
  int t = threadIdx.x;
  h[t] = 0; h2[t] = 0;
  __syncthreads();
  int base = blockIdx.x * BTILE;
  int lim = ne - base; if (lim > BTILE) lim = BTILE;
  for (int k = t; k < lim; k += 256)
    atomicAdd(&h[erow[base + k] >> 9], 1);
  __syncthreads();
  if (h[t] > 0) gb[t] = atomicAdd(&bcur[t], h[t]);
  __syncthreads();
  for (int k = t; k < lim; k += 256) {
    int dst = erow[base + k];
    int src = ecol[base + k];
    int b = dst >> 9;
    int r = atomicAdd(&h2[b], 1);
    pairs[gb[b] + r] = ((unsigned)(dst & 511) << 17) | (unsigned)src;
  }
}

// ---------------- kE: within-bucket rowptr build + exact placement ----------------
// 1 block (512 thr) per bucket: LDS hist over 512 local nodes, LDS scan,
// write fine rowptr (coalesced), place esrc via LDS cursors (L2-local scatter).
__global__ void __launch_bounds__(512)
kE_within(const unsigned* __restrict__ pairs, const int* __restrict__ bbase,
          int* __restrict__ rowptr, int* __restrict__ esrc, int nn) {
  __shared__ int lcnt[512], ts[512];
  int b = blockIdx.x;
  int t = threadIdx.x;
  int nstart = b << 9;
  int s = bbase[b], e = bbase[b + 1];
  int m = e - s;
  lcnt[t] = 0;
  __syncthreads();
  for (int i = t; i < m; i += 512)
    atomicAdd(&lcnt[pairs[s + i] >> 17], 1);
  __syncthreads();
  int v = lcnt[t];
  ts[t] = v;
  __syncthreads();
  for (int off = 1; off < 512; off <<= 1) {
    int u = (t >= off) ? ts[t - off] : 0;
    __syncthreads();
    ts[t] += u;
    __syncthreads();
  }
  int incl = ts[t];
  int n = nstart + t;
  if (n < nn) rowptr[n + 1] = s + incl;
  if (b == 0 && t == 0) rowptr[0] = 0;
  lcnt[t] = s + incl - v;   // global write cursor
  __syncthreads();
  for (int i = t; i < m; i += 512) {
    unsigned w = pairs[s + i];
    int p = atomicAdd(&lcnt[w >> 17], 1);
    esrc[p] = (int)(w & 0x1FFFFu);
  }
}

// ---------------- gather helper ----------------
static __device__ inline void chunk_acc(const ushort* __restrict__ xh, int sv,
                                        int cnt, int lane, float& a1, float& a2) {
  int k = 0;
  for (; k + 15 < cnt; k += 16) {
    float v[16];
#pragma unroll
    for (int u = 0; u < 16; ++u)
      v[u] = b2f(xh[__shfl(sv, k + u) * 64 + lane]);
#pragma unroll
    for (int u = 0; u < 16; ++u) { a1 += v[u]; a2 = fmaf(v[u], v[u], a2); }
  }
  for (; k + 3 < cnt; k += 4) {
    float v[4];
#pragma unroll
    for (int u = 0; u < 4; ++u)
      v[u] = b2f(xh[__shfl(sv, k + u) * 64 + lane]);
#pragma unroll
    for (int u = 0; u < 4; ++u) { a1 += v[u]; a2 = fmaf(v[u], v[u], a2); }
  }
  for (; k < cnt; ++k) {
    float v = b2f(xh[__shfl(sv, k) * 64 + lane]);
    a1 += v; a2 = fmaf(v, v, a2);
  }
}

// ---------------- fused aggregate + MFMA dense ----------------
__global__ void __launch_bounds__(256, 6)
k_agg_dense(const ushort* __restrict__ xh,
            const float* __restrict__ x,
            const int* __restrict__ rowptr,
            const int* __restrict__ esrc,
            const ushort* __restrict__ Bfrag,
            const float* __restrict__ bias,
            const float* __restrict__ avgp,
            float* __restrict__ out, int nn) {
  __shared__ __align__(16) ushort zs[16 * ZROW];
  const float avg = avgp[0];
  const int wave = threadIdx.x >> 6, lane = threadIdx.x & 63;
  const int n0 = blockIdx.x * 16;
  const int nw = n0 + wave * 4;

  int rpv = (lane < 5) ? rowptr[nw + lane] : 0;
  int e0 = __shfl(rpv, 0), e1 = __shfl(rpv, 1), e2 = __shfl(rpv, 2),
      e3 = __shfl(rpv, 3), e4 = __shfl(rpv, 4);
  int sv0 = (e0 + lane < e1) ? esrc[e0 + lane] : 0;
  int sv1 = (e1 + lane < e2) ? esrc[e1 + lane] : 0;
  int sv2 = (e2 + lane < e3) ? esrc[e2 + lane] : 0;
  int sv3 = (e3 + lane < e4) ? esrc[e3 + lane] : 0;

#define DO_NODE(J, SJ, EJ, SVJ)                                           \
  {                                                                       \
    int n = nw + J;                                                       \
    float a1 = 0.f, a2 = 0.f;                                             \
    int nb = EJ - SJ; if (nb > 64) nb = 64;                               \
    chunk_acc(xh, SVJ, nb, lane, a1, a2);                                 \
    for (int base = SJ + 64; base < EJ; base += 64) {                     \
      int c = EJ - base; if (c > 64) c = 64;                              \
      int sv = (base + lane < EJ) ? esrc[base + lane] : 0;                \
      chunk_acc(xh, sv, c, lane, a1, a2);                                 \
    }                                                                     \
    float m = a1;                                                         \
    float sd = sqrtf(fmaxf(a2 - m * m, 0.f) + 1e-7f);                     \
    float degf = (float)(EJ - SJ);                                        \
    float logd = logf(degf + 1.f);                                        \
    float f2 = logd / avg;                                                \
    float f3 = avg / (logd + 1e-7f);                                      \
    float xv = (n < nn) ? x[n * 64 + lane] : 0.f;                         \
    if (n >= nn) { m = 0.f; sd = 0.f; f2 = 0.f; f3 = 0.f; }               \
    ushort* zr = zs + (wave * 4 + J) * ZROW;                              \
    zr[lane]       = bfq(m);                                              \
    zr[64 + lane]  = bfq(m * f2);                                         \
    zr[128 + lane] = bfq(m * f3);                                         \
    zr[192 + lane] = bfq(sd);                                             \
    zr[256 + lane] = bfq(sd * f2);                                        \
    zr[320 + lane] = bfq(sd * f3);                                        \
    zr[384 + lane] = bfq(xv);                                             \
  }
  DO_NODE(0, e0, e1, sv0)
  DO_NODE(1, e1, e2, sv1)
  DO_NODE(2, e2, e3, sv2)
  DO_NODE(3, e3, e4, sv3)
#undef DO_NODE

  __syncthreads();

  const int r = lane & 15, kg = lane >> 4;
  const ushort* za = zs + r * ZROW + kg * 8;
  const ushort* bp = Bfrag + (wave * 64 + lane) * 8;
  f32x4 acc = {0.f, 0.f, 0.f, 0.f};
#pragma unroll
  for (int ks = 0; ks < KSTEPS; ++ks) {
    bf16x8 a = *(const bf16x8*)(za + ks * 32);
    bf16x8 b = *(const bf16x8*)(bp + ks * 2048);
    acc = __builtin_amdgcn_mfma_f32_16x16x32_bf16(a, b, acc, 0, 0, 0);
  }
  float bc = bias[wave * 16 + r];
#pragma unroll
  for (int i = 0; i < 4; ++i) {
    int n = n0 + kg * 4 + i;
    if (n < nn) out[n * 64 + wave * 16 + r] = acc[i] + bc;
  }
}

// ---------------- exact fp32 fixup for deg-0 nodes ----------------
__global__ void k_fixup(const int* __restrict__ rowptr, const float* __restrict__ x,
                        const float* __restrict__ Wt, const float* __restrict__ bias,
                        const float* __restrict__ avgp, float* __restrict__ out, int nn) {
  int n = blockIdx.x * 256 + threadIdx.x;
  if (n >= nn) return;
  if (rowptr[n + 1] != rowptr[n]) return;
  float avg = avgp[0];
  float sd = sqrtf(1e-7f);
  float f3 = avg / 1e-7f;
  for (int o = 0; o < 64; ++o) {
    float acc = bias[o];
    for (int d = 0; d < 64; ++d) {
      acc += sd * Wt[(192 + d) * 64 + o];
      acc += sd * f3 * Wt[(320 + d) * 64 + o];
      acc += x[n * 64 + d] * Wt[(384 + d) * 64 + o];
    }
    out[n * 64 + o] = acc;
  }
}

// ---------------- launch ----------------
extern "C" void kernel_launch(void* const* d_in, const int* in_sizes, int n_in,
                              void* d_out, int out_size, void* d_ws, size_t ws_size,
                              hipStream_t stream) {
  const float* x     = (const float*)d_in[0];
  const int*   erow  = (const int*)d_in[1];
  const int*   ecol  = (const int*)d_in[2];
  const float* pre_w = (const float*)d_in[3];
  const float* lin_w = (const float*)d_in[4];
  const float* bias  = (const float*)d_in[5];
  const float* avgp  = (const float*)d_in[6];
  float* out = (float*)d_out;

  int nn = in_sizes[0] / 64;
  int ne = in_sizes[1];
  int total = nn * 64;
  int nbk = (nn + 511) / 512;             // 196 buckets

  char* w = (char*)d_ws;
  auto align = [](size_t v) { return (v + 255) & ~(size_t)255; };
  size_t off = 0;
  ushort* xh     = (ushort*)(w + off); off = align(off + (size_t)total * 2);
  int* esrc      = (int*)(w + off); off = align(off + (size_t)ne * 4);
  unsigned* prs  = (unsigned*)(w + off); off = align(off + (size_t)ne * 4);
  int* rowptr    = (int*)(w + off); off = align(off + (size_t)(nn + 1) * 4);
  int* bucket_cnt= (int*)(w + off); size_t bc_off = off; off = align(off + NBMAX * 4);
  int* bbase     = (int*)(w + off); off = align(off + (NBMAX + 1) * 4);
  int* bcur      = (int*)(w + off); off = align(off + NBMAX * 4);
  float* Wt      = (float*)(w + off); off = align(off + (size_t)KTOT * 64 * 4);
  ushort* Bfr    = (ushort*)(w + off); off = align(off + (size_t)KSTEPS * 4 * 64 * 8 * 2);
  (void)ws_size;

  hipMemsetAsync(w + bc_off, 0, NBMAX * 4, stream);

  int gA = (total + 2047) / 2048;   // 3125; covers edges (782) and Wt (112)
  kA_prep<<<gA, 256, 0, stream>>>(x, erow, bucket_cnt, xh, pre_w, lin_w, Wt, Bfr,
                                  ne, total);
  kC_scan<<<1, NBMAX, 0, stream>>>(bucket_cnt, bbase, bcur, nbk);
  kD_binpass<<<(ne + BTILE - 1) / BTILE, 256, 0, stream>>>(erow, ecol, bcur, prs, ne);
  kE_within<<<nbk, 512, 0, stream>>>(prs, bbase, rowptr, esrc, nn);
  k_agg_dense<<<(nn + 15) / 16, 256, 0, stream>>>(xh, x, rowptr, esrc, Bfr, bias,
                                                  avgp, out, nn);
  k_fixup<<<(nn + 255) / 256, 256, 0, stream>>>(rowptr, x, Wt, bias, avgp, out, nn);
}